// Round 4
// baseline (81.692 us; speedup 1.0000x reference)
//
#include <hip/hip_runtime.h>

// EXL2Linear — faithful to the reference's (quirky) unpack indexing:
// only W[:, 0:64] receives quantized codes; W[:, 64:] == qzero broadcast.
// out[r,o] = s0(o) * sum_{j<64} x[r,j]*uq(o,j) + sum_g qzero[o,g]*gsum[r,g] + bias[o]
// K=96 bf16 MFMA GEMM, fully fused: one kernel reads x, builds per-block
// xg[16][96] in LDS, and writes out directly. weff[O][96] precomputed (L2-res).

constexpr int IFEAT  = 4096;
constexpr int OFEAT  = 4096;
constexpr int GROUPS = 32;   // IFEAT / 128
constexpr int KD     = 96;   // 64 quantized cols + 32 group sums
constexpr int KDP    = 104;  // padded LDS row (avoid bank conflicts on ds_read_b128)

using short8 = __attribute__((ext_vector_type(8))) short;
using f32x4  = __attribute__((ext_vector_type(4))) float;

static __device__ __forceinline__ unsigned short f2bf(float f) {
    union { float f; unsigned int u; } v; v.f = f;
    unsigned int lsb = (v.u >> 16) & 1;
    v.u += 0x7fff + lsb;           // round-to-nearest-even
    return (unsigned short)(v.u >> 16);
}

// ---------------- weff[O][96] bf16 (row-major, K contiguous)
__global__ __launch_bounds__(256) void prep_w_kernel(const int* __restrict__ qweight,
                                                     const float* __restrict__ qscale,
                                                     const int* __restrict__ qzero,
                                                     unsigned short* __restrict__ weff) {
    const int o = blockIdx.x * blockDim.x + threadIdx.x;
    if (o >= OFEAT) return;
    const float s0 = qscale[(size_t)o * GROUPS];  // group-0 scale
    const unsigned int* qw = (const unsigned int*)qweight + (size_t)o * (IFEAT / 8);
    unsigned int q[8];
    #pragma unroll
    for (int c = 0; c < 8; ++c) q[c] = qw[c];
    unsigned short* wr = weff + (size_t)o * KD;
    #pragma unroll
    for (int j = 0; j < 64; ++j) {
        const int c = j & 7;
        const int i = j >> 3;
        const float uq = (float)((q[c] >> (i * 4)) & 15u);
        wr[j] = f2bf(uq * s0);
    }
    #pragma unroll
    for (int g = 0; g < GROUPS; ++g) {
        wr[64 + g] = f2bf((float)qzero[(size_t)o * GROUPS + g]);
    }
}

// ---------------- Fused: block = 16 x-rows; stream x -> LDS xg -> MFMA -> out.
// 8 waves; wave wid reads rows {2wid, 2wid+1}; MFMA wave tile = 16 rows x 64 cols.
__global__ __launch_bounds__(512) void fused_kernel(const float* __restrict__ x,
                                                    const unsigned short* __restrict__ weff,
                                                    const float* __restrict__ bias,
                                                    float* __restrict__ out) {
    __shared__ unsigned short xs[16][KDP];
    const int t    = threadIdx.x;
    const int wid  = t >> 6;
    const int lane = t & 63;
    const int r0   = blockIdx.x * 16;

    // ---- read phase: rows 2wid, 2wid+1
    #pragma unroll
    for (int rr = 0; rr < 2; ++rr) {
        const int row = wid * 2 + rr;
        const float4* __restrict__ xrow = (const float4*)(x + (size_t)(r0 + row) * IFEAT);
        float4 v[16];
        #pragma unroll
        for (int i = 0; i < 16; ++i) v[i] = xrow[i * 64 + lane];   // cols 256i+4*lane
        #pragma unroll
        for (int i = 0; i < 16; ++i) {
            float s = v[i].x + v[i].y + v[i].z + v[i].w;
            #pragma unroll
            for (int off = 1; off <= 16; off <<= 1) s += __shfl_xor(s, off);
            if ((lane & 31) == 0)
                xs[row][64 + 2 * i + (lane >> 5)] = f2bf(s);        // group sums
        }
        if (lane < 16) {                                            // cols 0..63
            ushort4 p;
            p.x = f2bf(v[0].x); p.y = f2bf(v[0].y);
            p.z = f2bf(v[0].z); p.w = f2bf(v[0].w);
            *(ushort4*)&xs[row][4 * lane] = p;
        }
    }
    __syncthreads();

    // ---- MFMA phase: A-frags invariant over the whole o-loop (3 ds_reads)
    const int l15 = lane & 15;
    const int kq  = (lane >> 4) * 8;     // k-offset within a 32-wide K-step
    short8 a[3];
    #pragma unroll
    for (int ks = 0; ks < 3; ++ks)
        a[ks] = *(const short8*)&xs[l15][kq + 32 * ks];

    #pragma unroll 1
    for (int oi = 0; oi < 8; ++oi) {
        const int obase = oi * 512 + wid * 64;
        f32x4 acc[4] = {};
        #pragma unroll
        for (int ks = 0; ks < 3; ++ks) {
            #pragma unroll
            for (int sub = 0; sub < 4; ++sub) {
                const int oc = obase + sub * 16 + l15;
                const short8 b = *(const short8*)(weff + (size_t)oc * KD + kq + 32 * ks);
                acc[sub] = __builtin_amdgcn_mfma_f32_16x16x32_bf16(a[ks], b, acc[sub], 0, 0, 0);
            }
        }
        const int rbase = r0 + (lane >> 4) * 4;     // C: col=lane&15, row=(lane>>4)*4+i
        #pragma unroll
        for (int sub = 0; sub < 4; ++sub) {
            const int oc = obase + sub * 16 + l15;
            const float bb = bias[oc];
            #pragma unroll
            for (int i = 0; i < 4; ++i)
                out[(size_t)(rbase + i) * OFEAT + oc] = acc[sub][i] + bb;
        }
    }
}

extern "C" void kernel_launch(void* const* d_in, const int* in_sizes, int n_in,
                              void* d_out, int out_size, void* d_ws, size_t ws_size,
                              hipStream_t stream) {
    const float* x       = (const float*)d_in[0];
    const int*   qweight = (const int*)d_in[1];
    const float* qscale  = (const float*)d_in[2];
    const int*   qzero   = (const int*)d_in[3];
    const float* bias    = (const float*)d_in[4];
    float*       out     = (float*)d_out;

    const int rows = in_sizes[0] / IFEAT;  // B*S = 8192

    unsigned short* weff = (unsigned short*)d_ws;   // O*96 bf16 = 768 KB

    prep_w_kernel<<<OFEAT / 256, 256, 0, stream>>>(qweight, qscale, qzero, weff);
    fused_kernel<<<rows / 16, 512, 0, stream>>>(x, weff, bias, out);
}

// Round 5
// 62.506 us; speedup vs baseline: 1.3070x; 1.3070x over previous
//
#include <hip/hip_runtime.h>

// EXL2Linear — faithful to the reference's (quirky) unpack indexing:
// only W[:, 0:64] receives quantized codes; W[:, 64:] == qzero broadcast.
// out[r,o] = s0(o) * sum_{j<64} x[r,j]*uq(o,j) + sum_g qzero[o,g]*gsum[r,g] + bias[o]
// Collapsed to a K=96 bf16 MFMA GEMM: xg[rows][96] @ weff[O][96]^T.
// GEMM uses SWAPPED operands (A=weff, B=xg) so each lane's acc regs are 4
// consecutive output columns -> float4 stores instead of scalar.

constexpr int IFEAT  = 4096;
constexpr int OFEAT  = 4096;
constexpr int GROUPS = 32;   // IFEAT / 128
constexpr int KD     = 96;   // 64 quantized cols + 32 group sums
constexpr int WBLKS  = OFEAT / 256;  // 16 weff-prep blocks

using short8 = __attribute__((ext_vector_type(8))) short;
using f32x16 = __attribute__((ext_vector_type(16))) float;

static __device__ __forceinline__ unsigned short f2bf(float f) {
    union { float f; unsigned int u; } v; v.f = f;
    unsigned int lsb = (v.u >> 16) & 1;
    v.u += 0x7fff + lsb;           // round-to-nearest-even
    return (unsigned short)(v.u >> 16);
}

// ---------------- Fused prep: blocks [0,WBLKS) build weff[O][96];
// blocks [WBLKS, WBLKS+rows) build xg[row][96]. 8192+16 blocks = full TLP,
// read-bound at ~6.4 TB/s.
__global__ __launch_bounds__(256) void prep_kernel(const float* __restrict__ x,
                                                   const int* __restrict__ qweight,
                                                   const float* __restrict__ qscale,
                                                   const int* __restrict__ qzero,
                                                   unsigned short* __restrict__ xg,
                                                   unsigned short* __restrict__ weff) {
    const int t = threadIdx.x;
    if (blockIdx.x < WBLKS) {
        // ---- weff rows (dispatched first; tiny)
        const int o = blockIdx.x * 256 + t;
        const float s0 = qscale[(size_t)o * GROUPS];  // group-0 scale
        const unsigned int* qw = (const unsigned int*)qweight + (size_t)o * (IFEAT / 8);
        unsigned int q[8];
        #pragma unroll
        for (int c = 0; c < 8; ++c) q[c] = qw[c];
        unsigned short* wr = weff + (size_t)o * KD;
        #pragma unroll
        for (int j = 0; j < 64; ++j) {
            const int c = j & 7;
            const int i = j >> 3;
            const float uq = (float)((q[c] >> (i * 4)) & 15u);
            wr[j] = f2bf(uq * s0);
        }
        #pragma unroll
        for (int g = 0; g < GROUPS; ++g) {
            wr[64 + g] = f2bf((float)qzero[(size_t)o * GROUPS + g]);
        }
        return;
    }
    // ---- xg row
    const int row = blockIdx.x - WBLKS;
    const float4* __restrict__ x4 = (const float4*)(x + (size_t)row * IFEAT);
    unsigned short* __restrict__ xr = xg + (size_t)row * KD;

    #pragma unroll
    for (int i = 0; i < 4; ++i) {
        const float4 v = x4[i * 256 + t];
        float s = v.x + v.y + v.z + v.w;
        // one group = 32 lanes x 4 floats = 128 contiguous elems
        #pragma unroll
        for (int off = 1; off <= 16; off <<= 1) s += __shfl_xor(s, off);
        if ((t & 31) == 0) {
            const int g = i * 8 + (t >> 5);
            xr[64 + g] = f2bf(s);
        }
    }
    if (t < 64) xr[t] = f2bf(x[(size_t)row * IFEAT + t]);
}

// ---------------- GEMM: out[rows][OFEAT] = xg @ weff^T + bias via MFMA.
// Block = 4 waves = 128x128 tile (2x2 waves, each wave 64x64 = 2x2 of 32x32).
// No LDS: fragments are direct 16B global loads (xg/weff are L2-resident).
// Operands swapped: mfma(A=weff_frag, B=xg_frag) -> D[row=o_reg][col=r_lane],
// so per lane regs 4g..4g+3 = 4 consecutive out columns -> dwordx4 stores.
__global__ __launch_bounds__(256) void mfma_gemm_kernel(const unsigned short* __restrict__ xg,
                                                        const unsigned short* __restrict__ weff,
                                                        const float* __restrict__ bias,
                                                        float* __restrict__ out) {
    const int wid  = threadIdx.x >> 6;
    const int lane = threadIdx.x & 63;
    const int rbase = blockIdx.y * 128 + (wid >> 1) * 64;   // wave's 64 rows
    const int obase = blockIdx.x * 128 + (wid & 1) * 64;    // wave's 64 cols

    const int l31  = lane & 31;
    const int half = lane >> 5;       // 0 or 1
    const int koff = half * 8;

    // xg fragments (B operand): lane -> row rbase+32R+l31
    const short8* __restrict__ xp0 = (const short8*)(xg + (size_t)(rbase + l31) * KD + koff);
    const short8* __restrict__ xp1 = (const short8*)(xg + (size_t)(rbase + 32 + l31) * KD + koff);
    // weff fragments (A operand): lane -> row obase+32o+l31
    const short8* __restrict__ wp0 = (const short8*)(weff + (size_t)(obase + l31) * KD + koff);
    const short8* __restrict__ wp1 = (const short8*)(weff + (size_t)(obase + 32 + l31) * KD + koff);

    f32x16 acc[2][2] = {};   // [o-tile][r-tile]
    #pragma unroll
    for (int ks = 0; ks < 6; ++ks) {
        const short8 a0 = wp0[ks * 2];   // advance 16 shorts per K-step
        const short8 a1 = wp1[ks * 2];
        const short8 b0 = xp0[ks * 2];
        const short8 b1 = xp1[ks * 2];
        acc[0][0] = __builtin_amdgcn_mfma_f32_32x32x16_bf16(a0, b0, acc[0][0], 0, 0, 0);
        acc[0][1] = __builtin_amdgcn_mfma_f32_32x32x16_bf16(a0, b1, acc[0][1], 0, 0, 0);
        acc[1][0] = __builtin_amdgcn_mfma_f32_32x32x16_bf16(a1, b0, acc[1][0], 0, 0, 0);
        acc[1][1] = __builtin_amdgcn_mfma_f32_32x32x16_bf16(a1, b1, acc[1][1], 0, 0, 0);
    }

    // D layout (swapped): out_col = obase+32o + 8g+4*half + (reg&3), out_row = rbase+32R+l31
    #pragma unroll
    for (int o = 0; o < 2; ++o) {
        #pragma unroll
        for (int g = 0; g < 4; ++g) {
            const int col = obase + 32 * o + 8 * g + 4 * half;
            const float4 bb = *(const float4*)&bias[col];
            #pragma unroll
            for (int R = 0; R < 2; ++R) {
                const size_t row = (size_t)(rbase + 32 * R + l31);
                float4 v;
                v.x = acc[o][R][4 * g + 0] + bb.x;
                v.y = acc[o][R][4 * g + 1] + bb.y;
                v.z = acc[o][R][4 * g + 2] + bb.z;
                v.w = acc[o][R][4 * g + 3] + bb.w;
                *(float4*)&out[row * OFEAT + col] = v;
            }
        }
    }
}

extern "C" void kernel_launch(void* const* d_in, const int* in_sizes, int n_in,
                              void* d_out, int out_size, void* d_ws, size_t ws_size,
                              hipStream_t stream) {
    const float* x       = (const float*)d_in[0];
    const int*   qweight = (const int*)d_in[1];
    const float* qscale  = (const float*)d_in[2];
    const int*   qzero   = (const int*)d_in[3];
    const float* bias    = (const float*)d_in[4];
    float*       out     = (float*)d_out;

    const int rows = in_sizes[0] / IFEAT;  // B*S = 8192

    unsigned short* xg   = (unsigned short*)d_ws;              // rows*96 bf16
    unsigned short* weff = xg + (size_t)rows * KD;             // O*96 bf16

    prep_kernel<<<rows + WBLKS, 256, 0, stream>>>(x, qweight, qscale, qzero, xg, weff);

    dim3 grid(OFEAT / 128, rows / 128);
    mfma_gemm_kernel<<<grid, 256, 0, stream>>>(xg, weff, bias, out);
}